// Round 8
// baseline (364.980 us; speedup 1.0000x reference)
//
#include <hip/hip_runtime.h>
#include <hip/hip_cooperative_groups.h>
#include <math.h>

namespace cg = cooperative_groups;

// EfficientDet post-processing v8: ONE cooperative megakernel.
// P1 decode+transpose+zero -> P2 sliced hist -> P3 collect(inline pivot)
// -> P4 sort+mask+scan+compact -> P5 single-wave 90-way merge.

#define A_N   110484
#define C_N   90
#define KCAND 512
#define NBINS 8192        // 13-bit histogram bins (key >> 19)
#define KSH   19
#define MAXDET 100
#define IMG_F 768.0f
#define THRESH 0.05f
#define NS2   3                                   // hist/collect slices per class
#define VTOT  (A_N / 4)                           // 27621
#define VS3   (VTOT / NS2)                        // 9207 (exact)
#define CAND_CAP 2048
#define KEEP_CAP 100
#define T_TASKS ((A_N + 63) / 64)                 // 1727 transpose tiles
#define D_TASKS ((A_N + 1023) / 1024)             // 108 decode chunks
#define Z_TASKS 32
#define P1_TOTAL (T_TASKS + D_TASKS + Z_TASKS)
#define GRID  256

typedef unsigned int u32;
typedef unsigned long long u64;

__device__ __forceinline__ u32 fkey(float f) {
    u32 u = __float_as_uint(f);
    return (u & 0x80000000u) ? ~u : (u | 0x80000000u);
}
__device__ __forceinline__ float unfkey(u32 k) {
    u32 u = (k & 0x80000000u) ? (k ^ 0x80000000u) : ~k;
    return __uint_as_float(u);
}
__device__ __forceinline__ u64 shflx64(u64 v, int m) {
    u32 lo = (u32)__shfl_xor((int)(u32)v, m, 64);
    u32 hi = (u32)__shfl_xor((int)(v >> 32), m, 64);
    return ((u64)hi << 32) | lo;
}

struct SMemTr  { u32 tile[64 * 91]; };                          // 23.3 KB
struct SMemHi  { u32 h[NBINS]; };                               // 32 KB
struct SMemCol { u32 hist[NBINS]; u32 csum[1024]; u64 lbuf[CAND_CAP]; }; // 52 KB
struct SMemNms {
    u64 sortbuf[2][CAND_CAP];                                   // 32 KB (aliased by bmask)
    float bxx[KCAND], byy[KCAND], bzz[KCAND], bww[KCAND];
    float ar[KCAND], sc[KCAND];
    u32 keepf[16], wbase[17];
};                                                              // 45.2 KB
union SMem { SMemTr tr; SMemHi hi; SMemCol col; SMemNms nms; };

__global__ __launch_bounds__(1024, 4)
void mega_kernel(const float* __restrict__ anchors,
                 const float* __restrict__ reg,
                 const float* __restrict__ cls,
                 float4* __restrict__ boxes,
                 u32* __restrict__ keysT,
                 u32* __restrict__ ghist,
                 u32* __restrict__ cnt,
                 u64* __restrict__ candbuf,
                 u32* __restrict__ keptbuf,
                 u32* __restrict__ cnt2,
                 float* __restrict__ out) {
    __shared__ SMem sm;
    __shared__ u32 sPv;
    __shared__ int lcnt, gbase;
    cg::grid_group grid = cg::this_grid();
    const int tid = threadIdx.x;

    // ---------------- P1: transpose + decode + zero ----------------
    for (int t = blockIdx.x; t < P1_TOTAL; t += GRID) {
        if (t < T_TASKS) {
            __syncthreads();   // protect tile reuse across iterations
            const int a0 = t * 64;
            const int lim = min(64, A_N - a0);
            const int n = lim * C_N;
            const float* src = cls + (size_t)a0 * C_N;
            for (int i = tid; i < n; i += 1024) {
                float x = src[i];
                float s = 1.0f / (1.0f + expf(-x));
                u32 aa = (u32)i / C_N, c = (u32)i % C_N;
                sm.tr.tile[aa * 91 + c] = fkey(s);
            }
            __syncthreads();
            for (int j = tid; j < C_N * 64; j += 1024) {
                int c = j >> 6, aa = j & 63;
                if (aa < lim)
                    keysT[(size_t)c * A_N + a0 + aa] = sm.tr.tile[aa * 91 + c];
            }
        } else if (t < T_TASKS + D_TASKS) {
            int a = (t - T_TASKS) * 1024 + tid;
            if (a < A_N) {
                float4 an = ((const float4*)anchors)[a];
                float4 dl = ((const float4*)reg)[a];
                float wa = an.z - an.x, ha = an.w - an.y;
                float cx = an.x + 0.5f * wa + dl.x * wa;
                float cy = an.y + 0.5f * ha + dl.y * ha;
                float w = expf(dl.z) * wa;
                float h = expf(dl.w) * ha;
                float4 o;
                o.x = fminf(fmaxf(cx - 0.5f * w, 0.0f), IMG_F);
                o.y = fminf(fmaxf(cy - 0.5f * h, 0.0f), IMG_F);
                o.z = fminf(fmaxf(cx + 0.5f * w, 0.0f), IMG_F);
                o.w = fminf(fmaxf(cy + 0.5f * h, 0.0f), IMG_F);
                boxes[a] = o;
            }
        } else {
            const int z = t - T_TASKS - D_TASKS;
            uint4* g4 = (uint4*)ghist;
            const int tot4 = C_N * NBINS / 4;
            uint4 zero4; zero4.x = zero4.y = zero4.z = zero4.w = 0u;
            for (int i = z * 1024 + tid; i < tot4; i += Z_TASKS * 1024)
                g4[i] = zero4;
            if (z == 0 && tid < C_N) cnt[tid] = 0u;
        }
    }
    grid.sync();

    // ---------------- P2: sliced per-class histogram ----------------
    for (int t = blockIdx.x; t < C_N * NS2; t += GRID) {
        const int c = t / NS2, s = t % NS2;
        __syncthreads();
        for (int i = tid; i < NBINS; i += 1024) sm.hi.h[i] = 0;
        __syncthreads();
        const int lo = s * VS3, hiEnd = min(VTOT, lo + VS3);
        const uint4* kv = (const uint4*)(keysT + (size_t)c * A_N);
        for (int i = lo + tid; i < hiEnd; i += 1024) {
            uint4 k = kv[i];
            atomicAdd(&sm.hi.h[k.x >> KSH], 1u);
            atomicAdd(&sm.hi.h[k.y >> KSH], 1u);
            atomicAdd(&sm.hi.h[k.z >> KSH], 1u);
            atomicAdd(&sm.hi.h[k.w >> KSH], 1u);
        }
        __syncthreads();
        u32* gh = ghist + (size_t)c * NBINS;
        for (int i = tid; i < NBINS; i += 1024) {
            u32 v = sm.hi.h[i];
            if (v) atomicAdd(&gh[i], v);
        }
    }
    grid.sync();

    // ---------------- P3: collect with inline pivot ----------------
    for (int t = blockIdx.x; t < C_N * NS2; t += GRID) {
        const int c = t / NS2, s = t % NS2;
        __syncthreads();
        const u32* gh = ghist + (size_t)c * NBINS;
        for (int i = tid; i < NBINS; i += 1024) sm.col.hist[i] = gh[i];
        if (tid == 0) { sPv = 0; lcnt = 0; }
        __syncthreads();
        // pivot: descending 8-bin chunk sums + scan + local walk
        u32 own = 0; const int hi = NBINS - 1 - 8 * tid;
        #pragma unroll
        for (int j = 0; j < 8; ++j) own += sm.col.hist[hi - j];
        sm.col.csum[tid] = own;
        __syncthreads();
        for (int off = 1; off < 1024; off <<= 1) {
            u32 v = sm.col.csum[tid];
            u32 a = (tid >= off) ? sm.col.csum[tid - off] : 0u;
            __syncthreads();
            sm.col.csum[tid] = v + a;
            __syncthreads();
        }
        const u32 incl = sm.col.csum[tid], excl = incl - own;
        if (excl < (u32)KCAND && incl >= (u32)KCAND) {
            u32 cum = excl;
            for (int j = 0; j < 8; ++j) {
                u32 hv = sm.col.hist[hi - j];
                if (cum + hv >= (u32)KCAND) { sPv = (u32)(hi - j); break; }
                cum += hv;
            }
        }
        __syncthreads();
        const u32 P = sPv;
        const int lo = s * VS3, hiEnd = min(VTOT, lo + VS3);
        const uint4* kv = (const uint4*)(keysT + (size_t)c * A_N);
        for (int i = lo + tid; i < hiEnd; i += 1024) {
            uint4 k = kv[i];
            u32 base = (u32)(4 * i);
            if ((k.x >> KSH) >= P) {
                int p = atomicAdd(&lcnt, 1);
                if (p < CAND_CAP) sm.col.lbuf[p] = (((u64)(~k.x)) << 32) | base;
            }
            if ((k.y >> KSH) >= P) {
                int p = atomicAdd(&lcnt, 1);
                if (p < CAND_CAP) sm.col.lbuf[p] = (((u64)(~k.y)) << 32) | (base + 1);
            }
            if ((k.z >> KSH) >= P) {
                int p = atomicAdd(&lcnt, 1);
                if (p < CAND_CAP) sm.col.lbuf[p] = (((u64)(~k.z)) << 32) | (base + 2);
            }
            if ((k.w >> KSH) >= P) {
                int p = atomicAdd(&lcnt, 1);
                if (p < CAND_CAP) sm.col.lbuf[p] = (((u64)(~k.w)) << 32) | (base + 3);
            }
        }
        __syncthreads();
        const int n = min(lcnt, CAND_CAP);
        if (tid == 0) gbase = (int)atomicAdd(&cnt[c], (u32)n);
        __syncthreads();
        u64* cb = candbuf + (size_t)c * CAND_CAP;
        const int b = gbase;
        for (int i = tid; i < n; i += 1024) {
            int d = b + i;
            if (d < CAND_CAP) cb[d] = sm.col.lbuf[i];
        }
    }
    grid.sync();

    // ------- P4: sort + IoU mask + greedy scan + compact (90 blocks) -------
    if (blockIdx.x < C_N) {
        const int c = blockIdx.x;
        const int l = tid & 63, w = tid >> 6;
        const int i0 = 128 * w + l, i1 = i0 + 64;
        u32* bmask = (u32*)&sm.nms.sortbuf[0][0];

        const int n = min((int)cnt[c], CAND_CAP);
        const u64* cb = candbuf + (size_t)c * CAND_CAP;
        u64 v0 = (i0 < n) ? cb[i0] : ~0ULL;
        u64 v1 = (i1 < n) ? cb[i1] : ~0ULL;
        int p = 0;
        #pragma unroll
        for (u32 kk = 2; kk <= CAND_CAP; kk <<= 1) {
            #pragma unroll
            for (u32 j = kk >> 1; j > 0; j >>= 1) {
                if (j >= 128) {
                    sm.nms.sortbuf[p][i0] = v0; sm.nms.sortbuf[p][i1] = v1;
                    __syncthreads();
                    u64 w0 = sm.nms.sortbuf[p][i0 ^ j], w1 = sm.nms.sortbuf[p][i1 ^ j];
                    bool m0 = (((i0 & j) == 0) == ((i0 & kk) == 0));
                    bool m1 = (((i1 & j) == 0) == ((i1 & kk) == 0));
                    v0 = m0 ? (v0 < w0 ? v0 : w0) : (v0 > w0 ? v0 : w0);
                    v1 = m1 ? (v1 < w1 ? v1 : w1) : (v1 > w1 ? v1 : w1);
                    p ^= 1;
                } else if (j == 64) {
                    bool up = ((i0 & kk) == 0);
                    u64 mn = v0 < v1 ? v0 : v1, mx = v0 < v1 ? v1 : v0;
                    v0 = up ? mn : mx; v1 = up ? mx : mn;
                } else {
                    u64 w0 = shflx64(v0, (int)j), w1 = shflx64(v1, (int)j);
                    bool m0 = (((i0 & j) == 0) == ((i0 & kk) == 0));
                    bool m1 = (((i1 & j) == 0) == ((i1 & kk) == 0));
                    v0 = m0 ? (v0 < w0 ? v0 : w0) : (v0 > w0 ? v0 : w0);
                    v1 = m1 ? (v1 < w1 ? v1 : w1) : (v1 > w1 ? v1 : w1);
                }
            }
        }
        __syncthreads();   // sort in registers; sortbuf free for bmask

        if (w < 4) {
            u32 idx0 = (u32)v0, key0 = ~((u32)(v0 >> 32));
            u32 idx1 = (u32)v1, key1 = ~((u32)(v1 >> 32));
            sm.nms.sc[i0] = unfkey(key0); sm.nms.sc[i1] = unfkey(key1);
            float4 b0 = boxes[idx0], b1 = boxes[idx1];
            sm.nms.bxx[i0] = b0.x; sm.nms.byy[i0] = b0.y;
            sm.nms.bzz[i0] = b0.z; sm.nms.bww[i0] = b0.w;
            sm.nms.bxx[i1] = b1.x; sm.nms.byy[i1] = b1.y;
            sm.nms.bzz[i1] = b1.z; sm.nms.bww[i1] = b1.w;
            sm.nms.ar[i0] = (b0.z - b0.x) * (b0.w - b0.y);
            sm.nms.ar[i1] = (b1.z - b1.x) * (b1.w - b1.y);
        }
        for (int i = tid; i < KCAND * 16; i += 1024) bmask[i] = 0;
        if (tid < 16) sm.nms.keepf[tid] = 0;
        __syncthreads();

        {   // upper-triangular IoU mask, 2 threads per row
            const int i = tid & (KCAND - 1);
            const int half = tid >> 9;
            const int count = (KCAND - 1) - i;
            const int j0 = i + 1 + (half ? (count >> 1) : 0);
            const int j1 = half ? KCAND : (i + 1 + (count >> 1));
            const float bix = sm.nms.bxx[i], biy = sm.nms.byy[i];
            const float biz = sm.nms.bzz[i], biw = sm.nms.bww[i];
            const float ai = sm.nms.ar[i];
            u32 m[16];
            #pragma unroll
            for (int q = 0; q < 16; ++q) m[q] = 0;
            for (int j = j0; j < j1; ++j) {
                float xx1 = fmaxf(bix, sm.nms.bxx[j]), yy1 = fmaxf(biy, sm.nms.byy[j]);
                float xx2 = fminf(biz, sm.nms.bzz[j]), yy2 = fminf(biw, sm.nms.bww[j]);
                float inter = fmaxf(xx2 - xx1, 0.0f) * fmaxf(yy2 - yy1, 0.0f);
                float uni = ai + sm.nms.ar[j] - inter + 1e-8f;
                if (inter > 0.5f * uni) m[j >> 5] |= (1u << (j & 31));
            }
            #pragma unroll
            for (int q = 0; q < 16; ++q)
                if (m[q]) atomicOr(&bmask[i * 16 + q], m[q]);
        }
        __syncthreads();

        if (tid < 64) {   // greedy scan, wave 0
            const int lw = tid & 15;
            u32 removed = 0, keepw = 0;
            u32 rA[8], rB[8]; float sA[8], sB[8];
            #pragma unroll
            for (int k = 0; k < 8; ++k) { rA[k] = bmask[k * 16 + lw]; sA[k] = sm.nms.sc[k]; }
            #pragma unroll 1
            for (int ch = 0; ch < 64; ch += 2) {
                const int tb1 = (ch + 1) * 8;
                #pragma unroll
                for (int k = 0; k < 8; ++k) { rB[k] = bmask[(tb1 + k) * 16 + lw]; sB[k] = sm.nms.sc[tb1 + k]; }
                {
                    const int tb = ch * 8;
                    #pragma unroll
                    for (int k = 0; k < 8; ++k) {
                        const int t = tb + k;
                        u32 rw = (u32)__builtin_amdgcn_readlane((int)removed, t >> 5);
                        bool d = (sA[k] > THRESH) && (((rw >> (t & 31)) & 1u) == 0u);
                        removed |= d ? rA[k] : 0u;
                        keepw |= (d && (tid == (t >> 5))) ? (1u << (t & 31)) : 0u;
                    }
                }
                const int tb2 = (ch + 2 < 64) ? (ch + 2) * 8 : 0;
                #pragma unroll
                for (int k = 0; k < 8; ++k) { rA[k] = bmask[(tb2 + k) * 16 + lw]; sA[k] = sm.nms.sc[tb2 + k]; }
                {
                    #pragma unroll
                    for (int k = 0; k < 8; ++k) {
                        const int t = tb1 + k;
                        u32 rw = (u32)__builtin_amdgcn_readlane((int)removed, t >> 5);
                        bool d = (sB[k] > THRESH) && (((rw >> (t & 31)) & 1u) == 0u);
                        removed |= d ? rB[k] : 0u;
                        keepw |= (d && (tid == (t >> 5))) ? (1u << (t & 31)) : 0u;
                    }
                }
            }
            if (tid < 16) sm.nms.keepf[tid] = keepw;
        }
        __syncthreads();

        if (tid == 0) {   // compact prefix bases
            u32 t = 0;
            for (int q = 0; q < 16; ++q) { sm.nms.wbase[q] = t; t += __popc(sm.nms.keepf[q]); }
            sm.nms.wbase[16] = t;
            cnt2[c] = (t < (u32)KEEP_CAP) ? t : (u32)KEEP_CAP;
        }
        __syncthreads();
        if (tid < KCAND) {
            u32 word = sm.nms.keepf[tid >> 5];
            u32 bit = (u32)tid & 31u;
            if ((word >> bit) & 1u) {
                u32 rank = sm.nms.wbase[tid >> 5] + __popc(word & ((1u << bit) - 1u));
                if (rank < (u32)KEEP_CAP) {
                    float s = sm.nms.sc[tid];
                    uint4 a, b;
                    a.x = ~fkey(s);
                    a.y = (u32)(c * KCAND + tid);
                    a.z = __float_as_uint(sm.nms.bxx[tid]);
                    a.w = __float_as_uint(sm.nms.byy[tid]);
                    b.x = __float_as_uint(sm.nms.bzz[tid]);
                    b.y = __float_as_uint(sm.nms.bww[tid]);
                    b.z = __float_as_uint(s);
                    b.w = 0u;
                    uint4* e = (uint4*)(keptbuf + ((size_t)c * KEEP_CAP + rank) * 8);
                    e[0] = a; e[1] = b;
                }
            }
        }
    }
    grid.sync();

    // ---------- P5: single-wave 90-way sorted merge -> top-100 rows ----------
    if (blockIdx.x == 0 && tid < 64) {
        const int l = tid;
        for (int i = l; i < MAXDET * 7; i += 64) out[i] = 0.0f;

        const int cA = l, cB = l + 64;
        int nA = min((int)cnt2[cA], KEEP_CAP);
        int nB = (cB < C_N) ? min((int)cnt2[cB], KEEP_CAP) : 0;

        u64 curcA = ~0ULL, nxtcA = ~0ULL, curcB = ~0ULL, nxtcB = ~0ULL;
        float4 curbA, nxtbA, curbB, nxtbB;
        float cursA = 0, nxtsA = 0, cursB = 0, nxtsB = 0;
        int ptrA = 0, ptrB = 0;

        #define LOADE(c, p, comp, bx, s) { \
            const uint4* e_ = (const uint4*)(keptbuf + ((size_t)(c) * KEEP_CAP + (p)) * 8); \
            uint4 a_ = e_[0], b_ = e_[1]; \
            comp = ((u64)a_.x << 32) | a_.y; \
            bx.x = __uint_as_float(a_.z); bx.y = __uint_as_float(a_.w); \
            bx.z = __uint_as_float(b_.x); bx.w = __uint_as_float(b_.y); \
            s = __uint_as_float(b_.z); }

        if (nA > 0) LOADE(cA, 0, curcA, curbA, cursA);
        if (nA > 1) LOADE(cA, 1, nxtcA, nxtbA, nxtsA);
        if (nB > 0) LOADE(cB, 0, curcB, curbB, cursB);
        if (nB > 1) LOADE(cB, 1, nxtcB, nxtbB, nxtsB);

        for (int r = 0; r < MAXDET; ++r) {
            u64 g = curcA < curcB ? curcA : curcB;
            #pragma unroll
            for (int st = 1; st < 64; st <<= 1) {
                u64 o = shflx64(g, st);
                g = o < g ? o : g;
            }
            if (g == ~0ULL) break;
            if (curcA == g) {
                float* o = out + r * 7;
                o[0] = 0.0f; o[1] = curbA.x; o[2] = curbA.y; o[3] = curbA.z;
                o[4] = curbA.w; o[5] = cursA; o[6] = (float)(((u32)g) >> 9);
                curcA = nxtcA; curbA = nxtbA; cursA = nxtsA;
                ++ptrA;
                if (ptrA + 1 < nA) { LOADE(cA, ptrA + 1, nxtcA, nxtbA, nxtsA); }
                else nxtcA = ~0ULL;
            } else if (curcB == g) {
                float* o = out + r * 7;
                o[0] = 0.0f; o[1] = curbB.x; o[2] = curbB.y; o[3] = curbB.z;
                o[4] = curbB.w; o[5] = cursB; o[6] = (float)(((u32)g) >> 9);
                curcB = nxtcB; curbB = nxtbB; cursB = nxtsB;
                ++ptrB;
                if (ptrB + 1 < nB) { LOADE(cB, ptrB + 1, nxtcB, nxtbB, nxtsB); }
                else nxtcB = ~0ULL;
            }
        }
        #undef LOADE
    }
}

extern "C" void kernel_launch(void* const* d_in, const int* in_sizes, int n_in,
                              void* d_out, int out_size, void* d_ws, size_t ws_size,
                              hipStream_t stream) {
    const float* reg     = (const float*)d_in[1];
    const float* cls     = (const float*)d_in[2];
    const float* anchors = (const float*)d_in[3];
    float* out = (float*)d_out;

    char* ws = (char*)d_ws;
    size_t off = 0;
    auto alloc = [&](size_t bytes) -> void* {
        void* p = ws + off;
        off = (off + bytes + 255) & ~(size_t)255;
        return p;
    };
    u32*    keysT   = (u32*)   alloc((size_t)C_N * A_N * sizeof(u32));          // 39.8 MB
    float4* boxes   = (float4*)alloc((size_t)A_N * sizeof(float4));             // 1.77 MB
    u32*    ghist   = (u32*)   alloc((size_t)C_N * NBINS * sizeof(u32));        // 2.95 MB
    u32*    cnt     = (u32*)   alloc((size_t)C_N * sizeof(u32));
    u32*    cnt2    = (u32*)   alloc((size_t)C_N * sizeof(u32));
    u64*    candbuf = (u64*)   alloc((size_t)C_N * CAND_CAP * sizeof(u64));     // 1.47 MB
    u32*    keptbuf = (u32*)   alloc((size_t)C_N * KEEP_CAP * 8 * sizeof(u32)); // 288 KB
    (void)ws_size;

    void* args[] = { (void*)&anchors, (void*)&reg, (void*)&cls,
                     (void*)&boxes, (void*)&keysT, (void*)&ghist,
                     (void*)&cnt, (void*)&candbuf, (void*)&keptbuf,
                     (void*)&cnt2, (void*)&out };
    hipLaunchCooperativeKernel((void*)mega_kernel, dim3(GRID), dim3(1024),
                               args, 0, stream);
}

// Round 9
// 322.156 us; speedup vs baseline: 1.1329x; 1.1329x over previous
//
#include <hip/hip_runtime.h>
#include <math.h>

// EfficientDet post-processing v9 (3 launches).
// prep(transpose + zero done) -> select(per-class-slice local top-512, + decode
// blocks) -> snms(sort4096 + mask + scan + compact + last-block 90-way merge).

#define A_N   110484
#define C_N   90
#define KCAND 512
#define NBINS 8192        // 13-bit histogram bins (key >> 19)
#define KSH   19
#define MAXDET 100
#define IMG_F 768.0f
#define THRESH 0.05f
#define NS    4                                   // slices per class
#define VTOT  (A_N / 4)                           // 27621 vec4 units
#define VS4   ((VTOT + NS - 1) / NS)              // 6906
#define SL_CAP 1024                               // per-slice candidate cap
#define CAND_N (NS * SL_CAP)                      // 4096 per class
#define KEEP_CAP 100
#define T_BLKS ((A_N + 63) / 64)                  // 1727 transpose blocks
#define S_BLKS (C_N * NS)                         // 360 select blocks
#define D_BLKS ((A_N + 255) / 256)                // 432 decode blocks

typedef unsigned int u32;
typedef unsigned long long u64;

__device__ __forceinline__ u32 fkey(float f) {
    u32 u = __float_as_uint(f);
    return (u & 0x80000000u) ? ~u : (u | 0x80000000u);
}
__device__ __forceinline__ float unfkey(u32 k) {
    u32 u = (k & 0x80000000u) ? (k ^ 0x80000000u) : ~k;
    return __uint_as_float(u);
}
__device__ __forceinline__ u64 shflx64(u64 v, int m) {
    u32 lo = (u32)__shfl_xor((int)(u32)v, m, 64);
    u32 hi = (u32)__shfl_xor((int)(v >> 32), m, 64);
    return ((u64)hi << 32) | lo;
}

// ------- Stage 1: transpose (sigmoid->key) + zero done counter -------
__global__ __launch_bounds__(256)
void prep_kernel(const float* __restrict__ cls,
                 u32* __restrict__ keysT,
                 u32* __restrict__ done) {
    __shared__ u32 tile[64 * 91];   // 23.3 KB, stride 91 (odd) = conflict-free
    if (blockIdx.x >= T_BLKS) {
        if (threadIdx.x == 0) *done = 0u;
        return;
    }
    const int a0 = blockIdx.x * 64;
    const int lim = min(64, A_N - a0);
    const int n = lim * C_N;
    const float* src = cls + (size_t)a0 * C_N;
    for (int i = threadIdx.x; i < n; i += 256) {
        float x = src[i];
        float s = 1.0f / (1.0f + expf(-x));
        u32 aa = (u32)i / C_N, c = (u32)i % C_N;
        tile[aa * 91 + c] = fkey(s);
    }
    __syncthreads();
    for (int j = threadIdx.x; j < C_N * 64; j += 256) {
        int c = j >> 6, aa = j & 63;
        if (aa < lim)
            keysT[(size_t)c * A_N + a0 + aa] = tile[aa * 91 + c];
    }
}

// ---- Stage 2: per-(class,slice) local top-512 select (+ decode blocks) ----
// Local hist -> local pivot for K=512 -> collect >= pivot (cap 1024,
// sentinel-padded). Union over 4 slices is a superset of the class top-512.
__global__ __launch_bounds__(256)
void select_kernel(const u32* __restrict__ keysT,
                   const float* __restrict__ anchors,
                   const float* __restrict__ reg,
                   float4* __restrict__ boxes,
                   u64* __restrict__ candbuf) {
    __shared__ u32 hist[NBINS];    // 32 KB
    __shared__ u32 csum[256];
    __shared__ u64 lbuf[SL_CAP];   // 8 KB
    __shared__ u32 sPv;
    __shared__ int lcnt;
    const int tid = threadIdx.x;

    if (blockIdx.x >= S_BLKS) {    // decode blocks
        int a = (blockIdx.x - S_BLKS) * 256 + tid;
        if (a < A_N) {
            float4 an = ((const float4*)anchors)[a];
            float4 dl = ((const float4*)reg)[a];
            float wa = an.z - an.x, ha = an.w - an.y;
            float cx = an.x + 0.5f * wa + dl.x * wa;
            float cy = an.y + 0.5f * ha + dl.y * ha;
            float w = expf(dl.z) * wa;
            float h = expf(dl.w) * ha;
            float4 o;
            o.x = fminf(fmaxf(cx - 0.5f * w, 0.0f), IMG_F);
            o.y = fminf(fmaxf(cy - 0.5f * h, 0.0f), IMG_F);
            o.z = fminf(fmaxf(cx + 0.5f * w, 0.0f), IMG_F);
            o.w = fminf(fmaxf(cy + 0.5f * h, 0.0f), IMG_F);
            boxes[a] = o;
        }
        return;
    }
    const int c = blockIdx.x >> 2, s = blockIdx.x & 3;
    const int lo = s * VS4, hiEnd = min(VTOT, lo + VS4);
    const uint4* kv = (const uint4*)(keysT + (size_t)c * A_N);

    for (int i = tid; i < NBINS; i += 256) hist[i] = 0;
    if (tid == 0) { sPv = 0; lcnt = 0; }
    __syncthreads();
    for (int i = lo + tid; i < hiEnd; i += 256) {
        uint4 k = kv[i];
        atomicAdd(&hist[k.x >> KSH], 1u);
        atomicAdd(&hist[k.y >> KSH], 1u);
        atomicAdd(&hist[k.z >> KSH], 1u);
        atomicAdd(&hist[k.w >> KSH], 1u);
    }
    __syncthreads();
    // local pivot: descending 32-bin chunk sums + scan + local walk
    u32 own = 0; const int hi = NBINS - 1 - 32 * tid;
    #pragma unroll 4
    for (int j = 0; j < 32; ++j) own += hist[hi - j];
    csum[tid] = own;
    __syncthreads();
    for (int off = 1; off < 256; off <<= 1) {
        u32 v = csum[tid];
        u32 a = (tid >= off) ? csum[tid - off] : 0u;
        __syncthreads();
        csum[tid] = v + a;
        __syncthreads();
    }
    const u32 incl = csum[tid], excl = incl - own;
    if (excl < (u32)KCAND && incl >= (u32)KCAND) {
        u32 cum = excl;
        for (int j = 0; j < 32; ++j) {
            u32 hv = hist[hi - j];
            if (cum + hv >= (u32)KCAND) { sPv = (u32)(hi - j); break; }
            cum += hv;
        }
    }
    __syncthreads();
    const u32 P = sPv;
    for (int i = lo + tid; i < hiEnd; i += 256) {
        uint4 k = kv[i];
        u32 base = (u32)(4 * i);
        if ((k.x >> KSH) >= P) {
            int p = atomicAdd(&lcnt, 1);
            if (p < SL_CAP) lbuf[p] = (((u64)(~k.x)) << 32) | base;
        }
        if ((k.y >> KSH) >= P) {
            int p = atomicAdd(&lcnt, 1);
            if (p < SL_CAP) lbuf[p] = (((u64)(~k.y)) << 32) | (base + 1);
        }
        if ((k.z >> KSH) >= P) {
            int p = atomicAdd(&lcnt, 1);
            if (p < SL_CAP) lbuf[p] = (((u64)(~k.z)) << 32) | (base + 2);
        }
        if ((k.w >> KSH) >= P) {
            int p = atomicAdd(&lcnt, 1);
            if (p < SL_CAP) lbuf[p] = (((u64)(~k.w)) << 32) | (base + 3);
        }
    }
    __syncthreads();
    const int n = min(lcnt, SL_CAP);
    u64* cb = candbuf + (size_t)c * CAND_N + (size_t)s * SL_CAP;
    for (int i = tid; i < SL_CAP; i += 256)
        cb[i] = (i < n) ? lbuf[i] : ~0ULL;   // sentinel pad -> sorts to tail
}

// -- Stage 3: sort4096 + IoU mask + greedy scan + compact + last-block merge --
__global__ __launch_bounds__(1024)
void snms_kernel(const u64* __restrict__ candbuf,
                 const float4* __restrict__ boxes,
                 u32* __restrict__ keptbuf, u32* __restrict__ cnt2,
                 u32* __restrict__ done, float* __restrict__ out) {
    __shared__ u64 buf[CAND_N];            // 32 KB; reused as bmask after sort
    __shared__ float bxx[KCAND], byy[KCAND], bzz[KCAND], bww[KCAND];
    __shared__ float ar[KCAND], sc[KCAND]; // 12 KB SoA
    __shared__ u32 keepf[16], wbase[17];
    __shared__ int sIsLast;
    u32* bmask = (u32*)buf;                // 512 rows x 16 words = 32 KB
    const int c = blockIdx.x, tid = threadIdx.x;

    // --- in-place LDS bitonic sort of 4096 (asc = score desc, idx asc) ---
    const u64* cb = candbuf + (size_t)c * CAND_N;
    for (int i = tid; i < CAND_N; i += 1024) buf[i] = cb[i];
    __syncthreads();
    for (u32 kk = 2; kk <= (u32)CAND_N; kk <<= 1) {
        for (u32 j = kk >> 1; j > 0; j >>= 1) {
            for (u32 i = tid; i < (u32)CAND_N; i += 1024) {
                u32 ixj = i ^ j;
                if (ixj > i) {
                    u64 x = buf[i], y = buf[ixj];
                    bool up = ((i & kk) == 0);
                    if (up ? (x > y) : (x < y)) { buf[i] = y; buf[ixj] = x; }
                }
            }
            __syncthreads();
        }
    }
    // --- top-512 -> SoA (guaranteed real: each slice contributes >=512) ---
    if (tid < KCAND) {
        u64 comp = buf[tid];
        u32 idx = (u32)comp;
        u32 key = ~((u32)(comp >> 32));
        sc[tid] = unfkey(key);
        float4 b = boxes[idx];
        bxx[tid] = b.x; byy[tid] = b.y; bzz[tid] = b.z; bww[tid] = b.w;
        ar[tid] = (b.z - b.x) * (b.w - b.y);
    }
    __syncthreads();   // all buf reads done before bmask overwrites it
    for (int i = tid; i < KCAND * 16; i += 1024) bmask[i] = 0;
    if (tid < 16) keepf[tid] = 0;
    __syncthreads();

    // --- upper-triangular IoU mask, 2 threads per row ---
    {
        const int i = tid & (KCAND - 1);
        const int half = tid >> 9;
        const int count = (KCAND - 1) - i;
        const int j0 = i + 1 + (half ? (count >> 1) : 0);
        const int j1 = half ? KCAND : (i + 1 + (count >> 1));
        const float bix = bxx[i], biy = byy[i], biz = bzz[i], biw = bww[i];
        const float ai = ar[i];
        u32 m[16];
        #pragma unroll
        for (int q = 0; q < 16; ++q) m[q] = 0;
        for (int j = j0; j < j1; ++j) {
            float xx1 = fmaxf(bix, bxx[j]), yy1 = fmaxf(biy, byy[j]);
            float xx2 = fminf(biz, bzz[j]), yy2 = fminf(biw, bww[j]);
            float inter = fmaxf(xx2 - xx1, 0.0f) * fmaxf(yy2 - yy1, 0.0f);
            float uni = ai + ar[j] - inter + 1e-8f;
            if (inter > 0.5f * uni) m[j >> 5] |= (1u << (j & 31));
        }
        #pragma unroll
        for (int q = 0; q < 16; ++q)
            if (m[q]) atomicOr(&bmask[i * 16 + q], m[q]);
    }
    __syncthreads();

    // --- greedy scan, wave 0; register-pipelined rows + readlane chain ---
    if (tid < 64) {
        const int lw = tid & 15;
        u32 removed = 0, keepw = 0;
        u32 rA[8], rB[8]; float sA[8], sB[8];
        #pragma unroll
        for (int k = 0; k < 8; ++k) { rA[k] = bmask[k * 16 + lw]; sA[k] = sc[k]; }
        #pragma unroll 1
        for (int ch = 0; ch < 64; ch += 2) {
            const int tb1 = (ch + 1) * 8;
            #pragma unroll
            for (int k = 0; k < 8; ++k) { rB[k] = bmask[(tb1 + k) * 16 + lw]; sB[k] = sc[tb1 + k]; }
            {
                const int tb = ch * 8;
                #pragma unroll
                for (int k = 0; k < 8; ++k) {
                    const int t = tb + k;
                    u32 rw = (u32)__builtin_amdgcn_readlane((int)removed, t >> 5);
                    bool d = (sA[k] > THRESH) && (((rw >> (t & 31)) & 1u) == 0u);
                    removed |= d ? rA[k] : 0u;
                    keepw |= (d && (tid == (t >> 5))) ? (1u << (t & 31)) : 0u;
                }
            }
            const int tb2 = (ch + 2 < 64) ? (ch + 2) * 8 : 0;
            #pragma unroll
            for (int k = 0; k < 8; ++k) { rA[k] = bmask[(tb2 + k) * 16 + lw]; sA[k] = sc[tb2 + k]; }
            {
                #pragma unroll
                for (int k = 0; k < 8; ++k) {
                    const int t = tb1 + k;
                    u32 rw = (u32)__builtin_amdgcn_readlane((int)removed, t >> 5);
                    bool d = (sB[k] > THRESH) && (((rw >> (t & 31)) & 1u) == 0u);
                    removed |= d ? rB[k] : 0u;
                    keepw |= (d && (tid == (t >> 5))) ? (1u << (t & 31)) : 0u;
                }
            }
        }
        if (tid < 16) keepf[tid] = keepw;
    }
    __syncthreads();

    // --- compact kept (sorted order) to keptbuf, cap 100/class ---
    if (tid == 0) {
        u32 t = 0;
        for (int q = 0; q < 16; ++q) { wbase[q] = t; t += __popc(keepf[q]); }
        wbase[16] = t;
        cnt2[c] = (t < (u32)KEEP_CAP) ? t : (u32)KEEP_CAP;
    }
    __syncthreads();
    if (tid < KCAND) {
        u32 word = keepf[tid >> 5];
        u32 bit = (u32)tid & 31u;
        if ((word >> bit) & 1u) {
            u32 rank = wbase[tid >> 5] + __popc(word & ((1u << bit) - 1u));
            if (rank < (u32)KEEP_CAP) {
                float s = sc[tid];
                uint4 a, b;
                a.x = ~fkey(s);
                a.y = (u32)(c * KCAND + tid);
                a.z = __float_as_uint(bxx[tid]);
                a.w = __float_as_uint(byy[tid]);
                b.x = __float_as_uint(bzz[tid]);
                b.y = __float_as_uint(bww[tid]);
                b.z = __float_as_uint(s);
                b.w = 0u;
                uint4* e = (uint4*)(keptbuf + ((size_t)c * KEEP_CAP + rank) * 8);
                e[0] = a; e[1] = b;
            }
        }
    }
    __syncthreads();

    // --- last block to finish runs the 90-way merge (release/acquire) ---
    __threadfence();                       // release: keptbuf/cnt2 visible
    if (tid == 0) sIsLast = (atomicAdd(done, 1u) == (u32)(C_N - 1)) ? 1 : 0;
    __syncthreads();
    if (!sIsLast) return;
    __threadfence();                       // acquire: see other blocks' writes

    if (tid < 64) {
        const int l = tid;
        for (int i = l; i < MAXDET * 7; i += 64) out[i] = 0.0f;

        const int cA = l, cB = l + 64;
        int nA = min((int)cnt2[cA], KEEP_CAP);
        int nB = (cB < C_N) ? min((int)cnt2[cB], KEEP_CAP) : 0;

        u64 curcA = ~0ULL, nxtcA = ~0ULL, curcB = ~0ULL, nxtcB = ~0ULL;
        float4 curbA, nxtbA, curbB, nxtbB;
        float cursA = 0, nxtsA = 0, cursB = 0, nxtsB = 0;
        int ptrA = 0, ptrB = 0;

        #define LOADE(c, p, comp, bx, s) { \
            const uint4* e_ = (const uint4*)(keptbuf + ((size_t)(c) * KEEP_CAP + (p)) * 8); \
            uint4 a_ = e_[0], b_ = e_[1]; \
            comp = ((u64)a_.x << 32) | a_.y; \
            bx.x = __uint_as_float(a_.z); bx.y = __uint_as_float(a_.w); \
            bx.z = __uint_as_float(b_.x); bx.w = __uint_as_float(b_.y); \
            s = __uint_as_float(b_.z); }

        if (nA > 0) LOADE(cA, 0, curcA, curbA, cursA);
        if (nA > 1) LOADE(cA, 1, nxtcA, nxtbA, nxtsA);
        if (nB > 0) LOADE(cB, 0, curcB, curbB, cursB);
        if (nB > 1) LOADE(cB, 1, nxtcB, nxtbB, nxtsB);

        for (int r = 0; r < MAXDET; ++r) {
            u64 g = curcA < curcB ? curcA : curcB;
            #pragma unroll
            for (int st = 1; st < 64; st <<= 1) {
                u64 o = shflx64(g, st);
                g = o < g ? o : g;
            }
            if (g == ~0ULL) break;
            if (curcA == g) {
                float* o = out + r * 7;
                o[0] = 0.0f; o[1] = curbA.x; o[2] = curbA.y; o[3] = curbA.z;
                o[4] = curbA.w; o[5] = cursA; o[6] = (float)(((u32)g) >> 9);
                curcA = nxtcA; curbA = nxtbA; cursA = nxtsA;
                ++ptrA;
                if (ptrA + 1 < nA) { LOADE(cA, ptrA + 1, nxtcA, nxtbA, nxtsA); }
                else nxtcA = ~0ULL;
            } else if (curcB == g) {
                float* o = out + r * 7;
                o[0] = 0.0f; o[1] = curbB.x; o[2] = curbB.y; o[3] = curbB.z;
                o[4] = curbB.w; o[5] = cursB; o[6] = (float)(((u32)g) >> 9);
                curcB = nxtcB; curbB = nxtbB; cursB = nxtsB;
                ++ptrB;
                if (ptrB + 1 < nB) { LOADE(cB, ptrB + 1, nxtcB, nxtbB, nxtsB); }
                else nxtcB = ~0ULL;
            }
        }
        #undef LOADE
    }
}

extern "C" void kernel_launch(void* const* d_in, const int* in_sizes, int n_in,
                              void* d_out, int out_size, void* d_ws, size_t ws_size,
                              hipStream_t stream) {
    const float* reg     = (const float*)d_in[1];
    const float* cls     = (const float*)d_in[2];
    const float* anchors = (const float*)d_in[3];
    float* out = (float*)d_out;

    char* ws = (char*)d_ws;
    size_t off = 0;
    auto alloc = [&](size_t bytes) -> void* {
        void* p = ws + off;
        off = (off + bytes + 255) & ~(size_t)255;
        return p;
    };
    u32*    keysT   = (u32*)   alloc((size_t)C_N * A_N * sizeof(u32));          // 39.8 MB
    float4* boxes   = (float4*)alloc((size_t)A_N * sizeof(float4));             // 1.77 MB
    u64*    candbuf = (u64*)   alloc((size_t)C_N * CAND_N * sizeof(u64));       // 2.95 MB
    u32*    keptbuf = (u32*)   alloc((size_t)C_N * KEEP_CAP * 8 * sizeof(u32)); // 288 KB
    u32*    cnt2    = (u32*)   alloc((size_t)C_N * sizeof(u32));
    u32*    done    = (u32*)   alloc(sizeof(u32));
    (void)ws_size;

    prep_kernel<<<T_BLKS + 1, 256, 0, stream>>>(cls, keysT, done);
    select_kernel<<<S_BLKS + D_BLKS, 256, 0, stream>>>(keysT, anchors, reg, boxes, candbuf);
    snms_kernel<<<C_N, 1024, 0, stream>>>(candbuf, boxes, keptbuf, cnt2, done, out);
}

// Round 10
// 272.910 us; speedup vs baseline: 1.3374x; 1.1805x over previous
//
#include <hip/hip_runtime.h>
#include <math.h>

// EfficientDet post-processing v10 (3 launches).
// prep(transpose vec4) -> select(local top-512 per (class,slice), SORTED,
// + decode blocks) -> snms(resume-bitonic merge of 4 sorted runs + mask +
// scan + compact + last-block 90-way merge).

#define A_N   110484
#define C_N   90
#define KCAND 512
#define NBINS 8192        // 13-bit histogram bins (key >> 19)
#define KSH   19
#define MAXDET 100
#define IMG_F 768.0f
#define THRESH 0.05f
#define NS    4                                   // slices per class
#define VTOT  (A_N / 4)                           // 27621 vec4 units
#define VS4   ((VTOT + NS - 1) / NS)              // 6906
#define SL_CAP 1024                               // per-slice candidate cap
#define CAND_N (NS * KCAND)                       // 2048 per class (sorted runs)
#define KEEP_CAP 100
#define T_BLKS ((A_N + 63) / 64)                  // 1727 transpose blocks
#define S_BLKS (C_N * NS)                         // 360 select blocks
#define D_BLKS ((A_N + 255) / 256)                // 432 decode blocks

typedef unsigned int u32;
typedef unsigned long long u64;

__device__ __forceinline__ u32 fkey(float f) {
    u32 u = __float_as_uint(f);
    return (u & 0x80000000u) ? ~u : (u | 0x80000000u);
}
__device__ __forceinline__ float unfkey(u32 k) {
    u32 u = (k & 0x80000000u) ? (k ^ 0x80000000u) : ~k;
    return __uint_as_float(u);
}
__device__ __forceinline__ u64 shflx64(u64 v, int m) {
    u32 lo = (u32)__shfl_xor((int)(u32)v, m, 64);
    u32 hi = (u32)__shfl_xor((int)(v >> 32), m, 64);
    return ((u64)hi << 32) | lo;
}

// ------- Stage 1: transpose (sigmoid->key, vec4 loads) + zero done -------
__global__ __launch_bounds__(256)
void prep_kernel(const float* __restrict__ cls,
                 u32* __restrict__ keysT,
                 u32* __restrict__ done) {
    __shared__ u32 tile[64 * 91];   // 23.3 KB, stride 91 (odd) = conflict-free
    if (blockIdx.x >= T_BLKS) {
        if (threadIdx.x == 0) *done = 0u;
        return;
    }
    const int a0 = blockIdx.x * 64;
    const int lim = min(64, A_N - a0);           // 64 or 20; lim*90 % 4 == 0
    const int n4 = (lim * C_N) >> 2;
    const float4* src4 = (const float4*)(cls + (size_t)a0 * C_N);
    for (int i4 = threadIdx.x; i4 < n4; i4 += 256) {
        float4 x4 = src4[i4];
        const u32 base = (u32)(4 * i4);
        float xs[4] = { x4.x, x4.y, x4.z, x4.w };
        #pragma unroll
        for (int k = 0; k < 4; ++k) {
            u32 i = base + k;
            u32 aa = i / C_N, c = i % C_N;
            float s = 1.0f / (1.0f + expf(-xs[k]));
            tile[aa * 91 + c] = fkey(s);
        }
    }
    __syncthreads();
    for (int j = threadIdx.x; j < C_N * 64; j += 256) {
        int c = j >> 6, aa = j & 63;
        if (aa < lim)
            keysT[(size_t)c * A_N + a0 + aa] = tile[aa * 91 + c];
    }
}

// ---- Stage 2: per-(class,slice) exact sorted top-512 (+ decode blocks) ----
// hist -> pivot(K=512) -> collect(<=1024) -> hybrid bitonic 1024 sort ->
// emit top-512 asc (even slice) / desc (odd slice) for bitonic resume.
__global__ __launch_bounds__(256)
void select_kernel(const u32* __restrict__ keysT,
                   const float* __restrict__ anchors,
                   const float* __restrict__ reg,
                   float4* __restrict__ boxes,
                   u64* __restrict__ candbuf) {
    __shared__ u32 hist[NBINS];    // 32 KB
    __shared__ u32 csum[256];
    __shared__ u64 lbuf[SL_CAP];   // 8 KB
    __shared__ u32 sPv;
    __shared__ int lcnt;
    const int tid = threadIdx.x;

    if (blockIdx.x >= S_BLKS) {    // decode blocks
        int a = (blockIdx.x - S_BLKS) * 256 + tid;
        if (a < A_N) {
            float4 an = ((const float4*)anchors)[a];
            float4 dl = ((const float4*)reg)[a];
            float wa = an.z - an.x, ha = an.w - an.y;
            float cx = an.x + 0.5f * wa + dl.x * wa;
            float cy = an.y + 0.5f * ha + dl.y * ha;
            float w = expf(dl.z) * wa;
            float h = expf(dl.w) * ha;
            float4 o;
            o.x = fminf(fmaxf(cx - 0.5f * w, 0.0f), IMG_F);
            o.y = fminf(fmaxf(cy - 0.5f * h, 0.0f), IMG_F);
            o.z = fminf(fmaxf(cx + 0.5f * w, 0.0f), IMG_F);
            o.w = fminf(fmaxf(cy + 0.5f * h, 0.0f), IMG_F);
            boxes[a] = o;
        }
        return;
    }
    const int c = blockIdx.x >> 2, s = blockIdx.x & 3;
    const int lo = s * VS4, hiEnd = min(VTOT, lo + VS4);
    const uint4* kv = (const uint4*)(keysT + (size_t)c * A_N);

    for (int i = tid; i < NBINS; i += 256) hist[i] = 0;
    if (tid == 0) { sPv = 0; lcnt = 0; }
    __syncthreads();
    for (int i = lo + tid; i < hiEnd; i += 256) {
        uint4 k = kv[i];
        atomicAdd(&hist[k.x >> KSH], 1u);
        atomicAdd(&hist[k.y >> KSH], 1u);
        atomicAdd(&hist[k.z >> KSH], 1u);
        atomicAdd(&hist[k.w >> KSH], 1u);
    }
    __syncthreads();
    // pivot: descending 32-bin chunk sums + scan + local walk
    u32 own = 0; const int hi = NBINS - 1 - 32 * tid;
    #pragma unroll 4
    for (int j = 0; j < 32; ++j) own += hist[hi - j];
    csum[tid] = own;
    __syncthreads();
    for (int off = 1; off < 256; off <<= 1) {
        u32 v = csum[tid];
        u32 a = (tid >= off) ? csum[tid - off] : 0u;
        __syncthreads();
        csum[tid] = v + a;
        __syncthreads();
    }
    const u32 incl = csum[tid], excl = incl - own;
    if (excl < (u32)KCAND && incl >= (u32)KCAND) {
        u32 cum = excl;
        for (int j = 0; j < 32; ++j) {
            u32 hv = hist[hi - j];
            if (cum + hv >= (u32)KCAND) { sPv = (u32)(hi - j); break; }
            cum += hv;
        }
    }
    __syncthreads();
    const u32 P = sPv;
    for (int i = lo + tid; i < hiEnd; i += 256) {
        uint4 k = kv[i];
        u32 base = (u32)(4 * i);
        if ((k.x >> KSH) >= P) {
            int p = atomicAdd(&lcnt, 1);
            if (p < SL_CAP) lbuf[p] = (((u64)(~k.x)) << 32) | base;
        }
        if ((k.y >> KSH) >= P) {
            int p = atomicAdd(&lcnt, 1);
            if (p < SL_CAP) lbuf[p] = (((u64)(~k.y)) << 32) | (base + 1);
        }
        if ((k.z >> KSH) >= P) {
            int p = atomicAdd(&lcnt, 1);
            if (p < SL_CAP) lbuf[p] = (((u64)(~k.z)) << 32) | (base + 2);
        }
        if ((k.w >> KSH) >= P) {
            int p = atomicAdd(&lcnt, 1);
            if (p < SL_CAP) lbuf[p] = (((u64)(~k.w)) << 32) | (base + 3);
        }
    }
    __syncthreads();
    const int n = min(lcnt, SL_CAP);   // n >= 512 guaranteed by pivot
    for (int i = tid; i < SL_CAP; i += 256) if (i >= n) lbuf[i] = ~0ULL;
    __syncthreads();

    // --- hybrid bitonic 1024 sort: 4 waves x (4 regs x 64 lanes) ---
    // element ii[r] = 256*w + 64*r + l; j<=32 shuffle, j=64/128 in-lane,
    // j>=256 via lbuf in-place (2 barriers per LDS step, 3 LDS steps).
    {
        const int l = tid & 63, w = tid >> 6;
        int ii[4]; u64 v[4];
        #pragma unroll
        for (int r = 0; r < 4; ++r) { ii[r] = 256 * w + 64 * r + l; v[r] = lbuf[ii[r]]; }
        __syncthreads();
        #pragma unroll
        for (u32 kk = 2; kk <= 1024; kk <<= 1) {
            #pragma unroll
            for (u32 j = kk >> 1; j > 0; j >>= 1) {
                if (j >= 256) {
                    #pragma unroll
                    for (int r = 0; r < 4; ++r) lbuf[ii[r]] = v[r];
                    __syncthreads();
                    #pragma unroll
                    for (int r = 0; r < 4; ++r) {
                        u64 pv = lbuf[ii[r] ^ j];
                        bool up = ((ii[r] & kk) == 0);
                        bool m = (((ii[r] & j) == 0) == up);
                        v[r] = m ? (v[r] < pv ? v[r] : pv) : (v[r] > pv ? v[r] : pv);
                    }
                    __syncthreads();
                } else if (j >= 64) {
                    const int rx = (int)(j >> 6);   // 1 or 2
                    u64 nv[4];
                    #pragma unroll
                    for (int r = 0; r < 4; ++r) {
                        u64 pv = v[r ^ rx];
                        bool up = ((ii[r] & kk) == 0);
                        bool m = (((ii[r] & j) == 0) == up);
                        nv[r] = m ? (v[r] < pv ? v[r] : pv) : (v[r] > pv ? v[r] : pv);
                    }
                    #pragma unroll
                    for (int r = 0; r < 4; ++r) v[r] = nv[r];
                } else {
                    #pragma unroll
                    for (int r = 0; r < 4; ++r) {
                        u64 pv = shflx64(v[r], (int)j);
                        bool up = ((ii[r] & kk) == 0);
                        bool m = (((ii[r] & j) == 0) == up);
                        v[r] = m ? (v[r] < pv ? v[r] : pv) : (v[r] > pv ? v[r] : pv);
                    }
                }
            }
        }
        // emit top-512 (fully real); asc for even slice, desc for odd
        u64* cb = candbuf + (size_t)c * CAND_N + (size_t)s * KCAND;
        const bool rev = (s & 1);
        #pragma unroll
        for (int r = 0; r < 4; ++r) {
            if (ii[r] < KCAND) {
                int d = rev ? (KCAND - 1 - ii[r]) : ii[r];
                cb[d] = v[r];
            }
        }
    }
}

// -- Stage 3: resume-bitonic(2048) + mask + scan + compact + last-block merge --
__global__ __launch_bounds__(1024)
void snms_kernel(const u64* __restrict__ candbuf,
                 const float4* __restrict__ boxes,
                 u32* __restrict__ keptbuf, u32* __restrict__ cnt2,
                 u32* __restrict__ done, float* __restrict__ out) {
    __shared__ u64 sortbuf[2][CAND_N];     // 32 KB; reused as bmask after sort
    __shared__ float bxx[KCAND], byy[KCAND], bzz[KCAND], bww[KCAND];
    __shared__ float ar[KCAND], sc[KCAND];
    __shared__ u32 keepf[16], wbase[17];
    __shared__ int sIsLast;
    u32* bmask = (u32*)&sortbuf[0][0];     // 512 rows x 16 words = 32 KB
    const int c = blockIdx.x, tid = threadIdx.x;
    const int l = tid & 63, w = tid >> 6;
    const int i0 = 128 * w + l, i1 = i0 + 64;

    // input: 4 sorted runs of 512, alternating asc/desc = post-stage-512 state
    const u64* cb = candbuf + (size_t)c * CAND_N;
    u64 v0 = cb[i0], v1 = cb[i1];
    int p = 0;
    #pragma unroll
    for (u32 kk = 1024; kk <= (u32)CAND_N; kk <<= 1) {
        #pragma unroll
        for (u32 j = kk >> 1; j > 0; j >>= 1) {
            if (j >= 128) {
                sortbuf[p][i0] = v0; sortbuf[p][i1] = v1;
                __syncthreads();
                u64 w0 = sortbuf[p][i0 ^ j], w1 = sortbuf[p][i1 ^ j];
                bool m0 = (((i0 & j) == 0) == ((i0 & kk) == 0));
                bool m1 = (((i1 & j) == 0) == ((i1 & kk) == 0));
                v0 = m0 ? (v0 < w0 ? v0 : w0) : (v0 > w0 ? v0 : w0);
                v1 = m1 ? (v1 < w1 ? v1 : w1) : (v1 > w1 ? v1 : w1);
                p ^= 1;
            } else if (j == 64) {
                bool up = ((i0 & kk) == 0);
                u64 mn = v0 < v1 ? v0 : v1, mx = v0 < v1 ? v1 : v0;
                v0 = up ? mn : mx; v1 = up ? mx : mn;
            } else {
                u64 w0 = shflx64(v0, (int)j), w1 = shflx64(v1, (int)j);
                bool m0 = (((i0 & j) == 0) == ((i0 & kk) == 0));
                bool m1 = (((i1 & j) == 0) == ((i1 & kk) == 0));
                v0 = m0 ? (v0 < w0 ? v0 : w0) : (v0 > w0 ? v0 : w0);
                v1 = m1 ? (v1 < w1 ? v1 : w1) : (v1 > w1 ? v1 : w1);
            }
        }
    }
    __syncthreads();   // sort done in registers; sortbuf free for bmask

    // --- top-512 -> SoA; zero mask ---
    if (w < 4) {   // i0,i1 < 512
        u32 idx0 = (u32)v0, key0 = ~((u32)(v0 >> 32));
        u32 idx1 = (u32)v1, key1 = ~((u32)(v1 >> 32));
        sc[i0] = unfkey(key0); sc[i1] = unfkey(key1);
        float4 b0 = boxes[idx0], b1 = boxes[idx1];
        bxx[i0] = b0.x; byy[i0] = b0.y; bzz[i0] = b0.z; bww[i0] = b0.w;
        bxx[i1] = b1.x; byy[i1] = b1.y; bzz[i1] = b1.z; bww[i1] = b1.w;
        ar[i0] = (b0.z - b0.x) * (b0.w - b0.y);
        ar[i1] = (b1.z - b1.x) * (b1.w - b1.y);
    }
    for (int i = tid; i < KCAND * 16; i += 1024) bmask[i] = 0;
    if (tid < 16) keepf[tid] = 0;
    __syncthreads();

    // --- upper-triangular IoU mask, 2 threads per row ---
    {
        const int i = tid & (KCAND - 1);
        const int half = tid >> 9;
        const int count = (KCAND - 1) - i;
        const int j0 = i + 1 + (half ? (count >> 1) : 0);
        const int j1 = half ? KCAND : (i + 1 + (count >> 1));
        const float bix = bxx[i], biy = byy[i], biz = bzz[i], biw = bww[i];
        const float ai = ar[i];
        u32 m[16];
        #pragma unroll
        for (int q = 0; q < 16; ++q) m[q] = 0;
        for (int j = j0; j < j1; ++j) {
            float xx1 = fmaxf(bix, bxx[j]), yy1 = fmaxf(biy, byy[j]);
            float xx2 = fminf(biz, bzz[j]), yy2 = fminf(biw, bww[j]);
            float inter = fmaxf(xx2 - xx1, 0.0f) * fmaxf(yy2 - yy1, 0.0f);
            float uni = ai + ar[j] - inter + 1e-8f;
            if (inter > 0.5f * uni) m[j >> 5] |= (1u << (j & 31));
        }
        #pragma unroll
        for (int q = 0; q < 16; ++q)
            if (m[q]) atomicOr(&bmask[i * 16 + q], m[q]);
    }
    __syncthreads();

    // --- greedy scan, wave 0; register-pipelined rows + readlane chain ---
    if (tid < 64) {
        const int lw = tid & 15;
        u32 removed = 0, keepw = 0;
        u32 rA[8], rB[8]; float sA[8], sB[8];
        #pragma unroll
        for (int k = 0; k < 8; ++k) { rA[k] = bmask[k * 16 + lw]; sA[k] = sc[k]; }
        #pragma unroll 1
        for (int ch = 0; ch < 64; ch += 2) {
            const int tb1 = (ch + 1) * 8;
            #pragma unroll
            for (int k = 0; k < 8; ++k) { rB[k] = bmask[(tb1 + k) * 16 + lw]; sB[k] = sc[tb1 + k]; }
            {
                const int tb = ch * 8;
                #pragma unroll
                for (int k = 0; k < 8; ++k) {
                    const int t = tb + k;
                    u32 rw = (u32)__builtin_amdgcn_readlane((int)removed, t >> 5);
                    bool d = (sA[k] > THRESH) && (((rw >> (t & 31)) & 1u) == 0u);
                    removed |= d ? rA[k] : 0u;
                    keepw |= (d && (tid == (t >> 5))) ? (1u << (t & 31)) : 0u;
                }
            }
            const int tb2 = (ch + 2 < 64) ? (ch + 2) * 8 : 0;
            #pragma unroll
            for (int k = 0; k < 8; ++k) { rA[k] = bmask[(tb2 + k) * 16 + lw]; sA[k] = sc[tb2 + k]; }
            {
                #pragma unroll
                for (int k = 0; k < 8; ++k) {
                    const int t = tb1 + k;
                    u32 rw = (u32)__builtin_amdgcn_readlane((int)removed, t >> 5);
                    bool d = (sB[k] > THRESH) && (((rw >> (t & 31)) & 1u) == 0u);
                    removed |= d ? rB[k] : 0u;
                    keepw |= (d && (tid == (t >> 5))) ? (1u << (t & 31)) : 0u;
                }
            }
        }
        if (tid < 16) keepf[tid] = keepw;
    }
    __syncthreads();

    // --- compact kept (sorted order) to keptbuf, cap 100/class ---
    if (tid == 0) {
        u32 t = 0;
        for (int q = 0; q < 16; ++q) { wbase[q] = t; t += __popc(keepf[q]); }
        wbase[16] = t;
        cnt2[c] = (t < (u32)KEEP_CAP) ? t : (u32)KEEP_CAP;
    }
    __syncthreads();
    if (tid < KCAND) {
        u32 word = keepf[tid >> 5];
        u32 bit = (u32)tid & 31u;
        if ((word >> bit) & 1u) {
            u32 rank = wbase[tid >> 5] + __popc(word & ((1u << bit) - 1u));
            if (rank < (u32)KEEP_CAP) {
                float s = sc[tid];
                uint4 a, b;
                a.x = ~fkey(s);
                a.y = (u32)(c * KCAND + tid);
                a.z = __float_as_uint(bxx[tid]);
                a.w = __float_as_uint(byy[tid]);
                b.x = __float_as_uint(bzz[tid]);
                b.y = __float_as_uint(bww[tid]);
                b.z = __float_as_uint(s);
                b.w = 0u;
                uint4* e = (uint4*)(keptbuf + ((size_t)c * KEEP_CAP + rank) * 8);
                e[0] = a; e[1] = b;
            }
        }
    }
    __syncthreads();

    // --- last block to finish runs the 90-way merge (release/acquire) ---
    __threadfence();
    if (tid == 0) sIsLast = (atomicAdd(done, 1u) == (u32)(C_N - 1)) ? 1 : 0;
    __syncthreads();
    if (!sIsLast) return;
    __threadfence();

    if (tid < 64) {
        const int l2 = tid;
        for (int i = l2; i < MAXDET * 7; i += 64) out[i] = 0.0f;

        const int cA = l2, cB = l2 + 64;
        int nA = min((int)cnt2[cA], KEEP_CAP);
        int nB = (cB < C_N) ? min((int)cnt2[cB], KEEP_CAP) : 0;

        u64 curcA = ~0ULL, nxtcA = ~0ULL, curcB = ~0ULL, nxtcB = ~0ULL;
        float4 curbA, nxtbA, curbB, nxtbB;
        float cursA = 0, nxtsA = 0, cursB = 0, nxtsB = 0;
        int ptrA = 0, ptrB = 0;

        #define LOADE(c, p, comp, bx, s) { \
            const uint4* e_ = (const uint4*)(keptbuf + ((size_t)(c) * KEEP_CAP + (p)) * 8); \
            uint4 a_ = e_[0], b_ = e_[1]; \
            comp = ((u64)a_.x << 32) | a_.y; \
            bx.x = __uint_as_float(a_.z); bx.y = __uint_as_float(a_.w); \
            bx.z = __uint_as_float(b_.x); bx.w = __uint_as_float(b_.y); \
            s = __uint_as_float(b_.z); }

        if (nA > 0) LOADE(cA, 0, curcA, curbA, cursA);
        if (nA > 1) LOADE(cA, 1, nxtcA, nxtbA, nxtsA);
        if (nB > 0) LOADE(cB, 0, curcB, curbB, cursB);
        if (nB > 1) LOADE(cB, 1, nxtcB, nxtbB, nxtsB);

        for (int r = 0; r < MAXDET; ++r) {
            u64 g = curcA < curcB ? curcA : curcB;
            #pragma unroll
            for (int st = 1; st < 64; st <<= 1) {
                u64 o = shflx64(g, st);
                g = o < g ? o : g;
            }
            if (g == ~0ULL) break;
            if (curcA == g) {
                float* o = out + r * 7;
                o[0] = 0.0f; o[1] = curbA.x; o[2] = curbA.y; o[3] = curbA.z;
                o[4] = curbA.w; o[5] = cursA; o[6] = (float)(((u32)g) >> 9);
                curcA = nxtcA; curbA = nxtbA; cursA = nxtsA;
                ++ptrA;
                if (ptrA + 1 < nA) { LOADE(cA, ptrA + 1, nxtcA, nxtbA, nxtsA); }
                else nxtcA = ~0ULL;
            } else if (curcB == g) {
                float* o = out + r * 7;
                o[0] = 0.0f; o[1] = curbB.x; o[2] = curbB.y; o[3] = curbB.z;
                o[4] = curbB.w; o[5] = cursB; o[6] = (float)(((u32)g) >> 9);
                curcB = nxtcB; curbB = nxtbB; cursB = nxtsB;
                ++ptrB;
                if (ptrB + 1 < nB) { LOADE(cB, ptrB + 1, nxtcB, nxtbB, nxtsB); }
                else nxtcB = ~0ULL;
            }
        }
        #undef LOADE
    }
}

extern "C" void kernel_launch(void* const* d_in, const int* in_sizes, int n_in,
                              void* d_out, int out_size, void* d_ws, size_t ws_size,
                              hipStream_t stream) {
    const float* reg     = (const float*)d_in[1];
    const float* cls     = (const float*)d_in[2];
    const float* anchors = (const float*)d_in[3];
    float* out = (float*)d_out;

    char* ws = (char*)d_ws;
    size_t off = 0;
    auto alloc = [&](size_t bytes) -> void* {
        void* p = ws + off;
        off = (off + bytes + 255) & ~(size_t)255;
        return p;
    };
    u32*    keysT   = (u32*)   alloc((size_t)C_N * A_N * sizeof(u32));          // 39.8 MB
    float4* boxes   = (float4*)alloc((size_t)A_N * sizeof(float4));             // 1.77 MB
    u64*    candbuf = (u64*)   alloc((size_t)C_N * CAND_N * sizeof(u64));       // 1.47 MB
    u32*    keptbuf = (u32*)   alloc((size_t)C_N * KEEP_CAP * 8 * sizeof(u32)); // 288 KB
    u32*    cnt2    = (u32*)   alloc((size_t)C_N * sizeof(u32));
    u32*    done    = (u32*)   alloc(sizeof(u32));
    (void)ws_size;

    prep_kernel<<<T_BLKS + 1, 256, 0, stream>>>(cls, keysT, done);
    select_kernel<<<S_BLKS + D_BLKS, 256, 0, stream>>>(keysT, anchors, reg, boxes, candbuf);
    snms_kernel<<<C_N, 1024, 0, stream>>>(candbuf, boxes, keptbuf, cnt2, done, out);
}

// Round 11
// 216.574 us; speedup vs baseline: 1.6852x; 1.2601x over previous
//
#include <hip/hip_runtime.h>
#include <math.h>

// EfficientDet post-processing v11 (4 launches).
// prep(transpose vec4) -> select(sorted top-512 per (class,slice) + decode)
// -> snms(resume-bitonic + mask + scan + compact)  [no fence/merge tail]
// -> final(hist-select top-100 over <=9000 kept entries).

#define A_N   110484
#define C_N   90
#define KCAND 512
#define NBINS 8192        // 13-bit histogram bins (key >> 19)
#define KSH   19
#define MAXDET 100
#define IMG_F 768.0f
#define THRESH 0.05f
#define NS    4                                   // slices per class
#define VTOT  (A_N / 4)                           // 27621 vec4 units
#define VS4   ((VTOT + NS - 1) / NS)              // 6906
#define SL_CAP 1024                               // per-slice candidate cap
#define CAND_N (NS * KCAND)                       // 2048 per class (sorted runs)
#define KEEP_CAP 100
#define T_BLKS ((A_N + 63) / 64)                  // 1727 transpose blocks
#define S_BLKS (C_N * NS)                         // 360 select blocks
#define D_BLKS ((A_N + 255) / 256)                // 432 decode blocks
#define FCAP  512                                 // final collect capacity

typedef unsigned int u32;
typedef unsigned long long u64;

__device__ __forceinline__ u32 fkey(float f) {
    u32 u = __float_as_uint(f);
    return (u & 0x80000000u) ? ~u : (u | 0x80000000u);
}
__device__ __forceinline__ float unfkey(u32 k) {
    u32 u = (k & 0x80000000u) ? (k ^ 0x80000000u) : ~k;
    return __uint_as_float(u);
}
__device__ __forceinline__ u64 shflx64(u64 v, int m) {
    u32 lo = (u32)__shfl_xor((int)(u32)v, m, 64);
    u32 hi = (u32)__shfl_xor((int)(v >> 32), m, 64);
    return ((u64)hi << 32) | lo;
}

// ------- Stage 1: transpose (sigmoid->key, vec4 loads) -------
__global__ __launch_bounds__(256)
void prep_kernel(const float* __restrict__ cls,
                 u32* __restrict__ keysT) {
    __shared__ u32 tile[64 * 91];   // 23.3 KB, stride 91 (odd) = conflict-free
    const int a0 = blockIdx.x * 64;
    const int lim = min(64, A_N - a0);           // 64 or 20; lim*90 % 4 == 0
    const int n4 = (lim * C_N) >> 2;
    const float4* src4 = (const float4*)(cls + (size_t)a0 * C_N);
    for (int i4 = threadIdx.x; i4 < n4; i4 += 256) {
        float4 x4 = src4[i4];
        const u32 base = (u32)(4 * i4);
        float xs[4] = { x4.x, x4.y, x4.z, x4.w };
        #pragma unroll
        for (int k = 0; k < 4; ++k) {
            u32 i = base + k;
            u32 aa = i / C_N, c = i % C_N;
            float s = 1.0f / (1.0f + expf(-xs[k]));
            tile[aa * 91 + c] = fkey(s);
        }
    }
    __syncthreads();
    for (int j = threadIdx.x; j < C_N * 64; j += 256) {
        int c = j >> 6, aa = j & 63;
        if (aa < lim)
            keysT[(size_t)c * A_N + a0 + aa] = tile[aa * 91 + c];
    }
}

// ---- Stage 2: per-(class,slice) exact sorted top-512 (+ decode blocks) ----
__global__ __launch_bounds__(256)
void select_kernel(const u32* __restrict__ keysT,
                   const float* __restrict__ anchors,
                   const float* __restrict__ reg,
                   float4* __restrict__ boxes,
                   u64* __restrict__ candbuf) {
    __shared__ u32 hist[NBINS];    // 32 KB
    __shared__ u32 csum[256];
    __shared__ u64 lbuf[SL_CAP];   // 8 KB
    __shared__ u32 sPv;
    __shared__ int lcnt;
    const int tid = threadIdx.x;

    if (blockIdx.x >= S_BLKS) {    // decode blocks
        int a = (blockIdx.x - S_BLKS) * 256 + tid;
        if (a < A_N) {
            float4 an = ((const float4*)anchors)[a];
            float4 dl = ((const float4*)reg)[a];
            float wa = an.z - an.x, ha = an.w - an.y;
            float cx = an.x + 0.5f * wa + dl.x * wa;
            float cy = an.y + 0.5f * ha + dl.y * ha;
            float w = expf(dl.z) * wa;
            float h = expf(dl.w) * ha;
            float4 o;
            o.x = fminf(fmaxf(cx - 0.5f * w, 0.0f), IMG_F);
            o.y = fminf(fmaxf(cy - 0.5f * h, 0.0f), IMG_F);
            o.z = fminf(fmaxf(cx + 0.5f * w, 0.0f), IMG_F);
            o.w = fminf(fmaxf(cy + 0.5f * h, 0.0f), IMG_F);
            boxes[a] = o;
        }
        return;
    }
    const int c = blockIdx.x >> 2, s = blockIdx.x & 3;
    const int lo = s * VS4, hiEnd = min(VTOT, lo + VS4);
    const uint4* kv = (const uint4*)(keysT + (size_t)c * A_N);

    for (int i = tid; i < NBINS; i += 256) hist[i] = 0;
    if (tid == 0) { sPv = 0; lcnt = 0; }
    __syncthreads();
    for (int i = lo + tid; i < hiEnd; i += 256) {
        uint4 k = kv[i];
        atomicAdd(&hist[k.x >> KSH], 1u);
        atomicAdd(&hist[k.y >> KSH], 1u);
        atomicAdd(&hist[k.z >> KSH], 1u);
        atomicAdd(&hist[k.w >> KSH], 1u);
    }
    __syncthreads();
    u32 own = 0; const int hi = NBINS - 1 - 32 * tid;
    #pragma unroll 4
    for (int j = 0; j < 32; ++j) own += hist[hi - j];
    csum[tid] = own;
    __syncthreads();
    for (int off = 1; off < 256; off <<= 1) {
        u32 v = csum[tid];
        u32 a = (tid >= off) ? csum[tid - off] : 0u;
        __syncthreads();
        csum[tid] = v + a;
        __syncthreads();
    }
    const u32 incl = csum[tid], excl = incl - own;
    if (excl < (u32)KCAND && incl >= (u32)KCAND) {
        u32 cum = excl;
        for (int j = 0; j < 32; ++j) {
            u32 hv = hist[hi - j];
            if (cum + hv >= (u32)KCAND) { sPv = (u32)(hi - j); break; }
            cum += hv;
        }
    }
    __syncthreads();
    const u32 P = sPv;
    for (int i = lo + tid; i < hiEnd; i += 256) {
        uint4 k = kv[i];
        u32 base = (u32)(4 * i);
        if ((k.x >> KSH) >= P) {
            int p = atomicAdd(&lcnt, 1);
            if (p < SL_CAP) lbuf[p] = (((u64)(~k.x)) << 32) | base;
        }
        if ((k.y >> KSH) >= P) {
            int p = atomicAdd(&lcnt, 1);
            if (p < SL_CAP) lbuf[p] = (((u64)(~k.y)) << 32) | (base + 1);
        }
        if ((k.z >> KSH) >= P) {
            int p = atomicAdd(&lcnt, 1);
            if (p < SL_CAP) lbuf[p] = (((u64)(~k.z)) << 32) | (base + 2);
        }
        if ((k.w >> KSH) >= P) {
            int p = atomicAdd(&lcnt, 1);
            if (p < SL_CAP) lbuf[p] = (((u64)(~k.w)) << 32) | (base + 3);
        }
    }
    __syncthreads();
    const int n = min(lcnt, SL_CAP);   // n >= 512 guaranteed by pivot
    for (int i = tid; i < SL_CAP; i += 256) if (i >= n) lbuf[i] = ~0ULL;
    __syncthreads();

    // --- hybrid bitonic 1024 sort: 4 waves x (4 regs x 64 lanes) ---
    {
        const int l = tid & 63, w = tid >> 6;
        int ii[4]; u64 v[4];
        #pragma unroll
        for (int r = 0; r < 4; ++r) { ii[r] = 256 * w + 64 * r + l; v[r] = lbuf[ii[r]]; }
        __syncthreads();
        #pragma unroll
        for (u32 kk = 2; kk <= 1024; kk <<= 1) {
            #pragma unroll
            for (u32 j = kk >> 1; j > 0; j >>= 1) {
                if (j >= 256) {
                    #pragma unroll
                    for (int r = 0; r < 4; ++r) lbuf[ii[r]] = v[r];
                    __syncthreads();
                    #pragma unroll
                    for (int r = 0; r < 4; ++r) {
                        u64 pv = lbuf[ii[r] ^ j];
                        bool up = ((ii[r] & kk) == 0);
                        bool m = (((ii[r] & j) == 0) == up);
                        v[r] = m ? (v[r] < pv ? v[r] : pv) : (v[r] > pv ? v[r] : pv);
                    }
                    __syncthreads();
                } else if (j >= 64) {
                    const int rx = (int)(j >> 6);   // 1 or 2
                    u64 nv[4];
                    #pragma unroll
                    for (int r = 0; r < 4; ++r) {
                        u64 pv = v[r ^ rx];
                        bool up = ((ii[r] & kk) == 0);
                        bool m = (((ii[r] & j) == 0) == up);
                        nv[r] = m ? (v[r] < pv ? v[r] : pv) : (v[r] > pv ? v[r] : pv);
                    }
                    #pragma unroll
                    for (int r = 0; r < 4; ++r) v[r] = nv[r];
                } else {
                    #pragma unroll
                    for (int r = 0; r < 4; ++r) {
                        u64 pv = shflx64(v[r], (int)j);
                        bool up = ((ii[r] & kk) == 0);
                        bool m = (((ii[r] & j) == 0) == up);
                        v[r] = m ? (v[r] < pv ? v[r] : pv) : (v[r] > pv ? v[r] : pv);
                    }
                }
            }
        }
        u64* cb = candbuf + (size_t)c * CAND_N + (size_t)s * KCAND;
        const bool rev = (s & 1);
        #pragma unroll
        for (int r = 0; r < 4; ++r) {
            if (ii[r] < KCAND) {
                int d = rev ? (KCAND - 1 - ii[r]) : ii[r];
                cb[d] = v[r];
            }
        }
    }
}

// ---- Stage 3: resume-bitonic(2048) + mask + scan + compact ----
__global__ __launch_bounds__(1024)
void snms_kernel(const u64* __restrict__ candbuf,
                 const float4* __restrict__ boxes,
                 u32* __restrict__ keptbuf, u32* __restrict__ cnt2) {
    __shared__ u64 sortbuf[2][CAND_N];     // 32 KB; reused as bmask after sort
    __shared__ float bxx[KCAND], byy[KCAND], bzz[KCAND], bww[KCAND];
    __shared__ float ar[KCAND], sc[KCAND];
    __shared__ u32 keepf[16], wbase[17];
    u32* bmask = (u32*)&sortbuf[0][0];     // 512 rows x 16 words = 32 KB
    const int c = blockIdx.x, tid = threadIdx.x;
    const int l = tid & 63, w = tid >> 6;
    const int i0 = 128 * w + l, i1 = i0 + 64;

    // input: 4 sorted runs of 512, alternating asc/desc = post-stage-512 state
    const u64* cb = candbuf + (size_t)c * CAND_N;
    u64 v0 = cb[i0], v1 = cb[i1];
    int p = 0;
    #pragma unroll
    for (u32 kk = 1024; kk <= (u32)CAND_N; kk <<= 1) {
        #pragma unroll
        for (u32 j = kk >> 1; j > 0; j >>= 1) {
            if (j >= 128) {
                sortbuf[p][i0] = v0; sortbuf[p][i1] = v1;
                __syncthreads();
                u64 w0 = sortbuf[p][i0 ^ j], w1 = sortbuf[p][i1 ^ j];
                bool m0 = (((i0 & j) == 0) == ((i0 & kk) == 0));
                bool m1 = (((i1 & j) == 0) == ((i1 & kk) == 0));
                v0 = m0 ? (v0 < w0 ? v0 : w0) : (v0 > w0 ? v0 : w0);
                v1 = m1 ? (v1 < w1 ? v1 : w1) : (v1 > w1 ? v1 : w1);
                p ^= 1;
            } else if (j == 64) {
                bool up = ((i0 & kk) == 0);
                u64 mn = v0 < v1 ? v0 : v1, mx = v0 < v1 ? v1 : v0;
                v0 = up ? mn : mx; v1 = up ? mx : mn;
            } else {
                u64 w0 = shflx64(v0, (int)j), w1 = shflx64(v1, (int)j);
                bool m0 = (((i0 & j) == 0) == ((i0 & kk) == 0));
                bool m1 = (((i1 & j) == 0) == ((i1 & kk) == 0));
                v0 = m0 ? (v0 < w0 ? v0 : w0) : (v0 > w0 ? v0 : w0);
                v1 = m1 ? (v1 < w1 ? v1 : w1) : (v1 > w1 ? v1 : w1);
            }
        }
    }
    __syncthreads();   // sort done in registers; sortbuf free for bmask

    // --- top-512 -> SoA; zero mask ---
    if (w < 4) {   // i0,i1 < 512
        u32 idx0 = (u32)v0, key0 = ~((u32)(v0 >> 32));
        u32 idx1 = (u32)v1, key1 = ~((u32)(v1 >> 32));
        sc[i0] = unfkey(key0); sc[i1] = unfkey(key1);
        float4 b0 = boxes[idx0], b1 = boxes[idx1];
        bxx[i0] = b0.x; byy[i0] = b0.y; bzz[i0] = b0.z; bww[i0] = b0.w;
        bxx[i1] = b1.x; byy[i1] = b1.y; bzz[i1] = b1.z; bww[i1] = b1.w;
        ar[i0] = (b0.z - b0.x) * (b0.w - b0.y);
        ar[i1] = (b1.z - b1.x) * (b1.w - b1.y);
    }
    for (int i = tid; i < KCAND * 16; i += 1024) bmask[i] = 0;
    if (tid < 16) keepf[tid] = 0;
    __syncthreads();

    // --- upper-triangular IoU mask, 2 threads per row ---
    {
        const int i = tid & (KCAND - 1);
        const int half = tid >> 9;
        const int count = (KCAND - 1) - i;
        const int j0 = i + 1 + (half ? (count >> 1) : 0);
        const int j1 = half ? KCAND : (i + 1 + (count >> 1));
        const float bix = bxx[i], biy = byy[i], biz = bzz[i], biw = bww[i];
        const float ai = ar[i];
        u32 m[16];
        #pragma unroll
        for (int q = 0; q < 16; ++q) m[q] = 0;
        for (int j = j0; j < j1; ++j) {
            float xx1 = fmaxf(bix, bxx[j]), yy1 = fmaxf(biy, byy[j]);
            float xx2 = fminf(biz, bzz[j]), yy2 = fminf(biw, bww[j]);
            float inter = fmaxf(xx2 - xx1, 0.0f) * fmaxf(yy2 - yy1, 0.0f);
            float uni = ai + ar[j] - inter + 1e-8f;
            if (inter > 0.5f * uni) m[j >> 5] |= (1u << (j & 31));
        }
        #pragma unroll
        for (int q = 0; q < 16; ++q)
            if (m[q]) atomicOr(&bmask[i * 16 + q], m[q]);
    }
    __syncthreads();

    // --- greedy scan, wave 0; register-pipelined rows + readlane chain ---
    if (tid < 64) {
        const int lw = tid & 15;
        u32 removed = 0, keepw = 0;
        u32 rA[8], rB[8]; float sA[8], sB[8];
        #pragma unroll
        for (int k = 0; k < 8; ++k) { rA[k] = bmask[k * 16 + lw]; sA[k] = sc[k]; }
        #pragma unroll 1
        for (int ch = 0; ch < 64; ch += 2) {
            const int tb1 = (ch + 1) * 8;
            #pragma unroll
            for (int k = 0; k < 8; ++k) { rB[k] = bmask[(tb1 + k) * 16 + lw]; sB[k] = sc[tb1 + k]; }
            {
                const int tb = ch * 8;
                #pragma unroll
                for (int k = 0; k < 8; ++k) {
                    const int t = tb + k;
                    u32 rw = (u32)__builtin_amdgcn_readlane((int)removed, t >> 5);
                    bool d = (sA[k] > THRESH) && (((rw >> (t & 31)) & 1u) == 0u);
                    removed |= d ? rA[k] : 0u;
                    keepw |= (d && (tid == (t >> 5))) ? (1u << (t & 31)) : 0u;
                }
            }
            const int tb2 = (ch + 2 < 64) ? (ch + 2) * 8 : 0;
            #pragma unroll
            for (int k = 0; k < 8; ++k) { rA[k] = bmask[(tb2 + k) * 16 + lw]; sA[k] = sc[tb2 + k]; }
            {
                #pragma unroll
                for (int k = 0; k < 8; ++k) {
                    const int t = tb1 + k;
                    u32 rw = (u32)__builtin_amdgcn_readlane((int)removed, t >> 5);
                    bool d = (sB[k] > THRESH) && (((rw >> (t & 31)) & 1u) == 0u);
                    removed |= d ? rB[k] : 0u;
                    keepw |= (d && (tid == (t >> 5))) ? (1u << (t & 31)) : 0u;
                }
            }
        }
        if (tid < 16) keepf[tid] = keepw;
    }
    __syncthreads();

    // --- compact kept (sorted order) to keptbuf, cap 100/class ---
    if (tid == 0) {
        u32 t = 0;
        for (int q = 0; q < 16; ++q) { wbase[q] = t; t += __popc(keepf[q]); }
        wbase[16] = t;
        cnt2[c] = (t < (u32)KEEP_CAP) ? t : (u32)KEEP_CAP;
    }
    __syncthreads();
    if (tid < KCAND) {
        u32 word = keepf[tid >> 5];
        u32 bit = (u32)tid & 31u;
        if ((word >> bit) & 1u) {
            u32 rank = wbase[tid >> 5] + __popc(word & ((1u << bit) - 1u));
            if (rank < (u32)KEEP_CAP) {
                float s = sc[tid];
                uint4 a, b;
                a.x = ~fkey(s);
                a.y = (u32)(c * KCAND + tid);
                a.z = __float_as_uint(bxx[tid]);
                a.w = __float_as_uint(byy[tid]);
                b.x = __float_as_uint(bzz[tid]);
                b.y = __float_as_uint(bww[tid]);
                b.z = __float_as_uint(s);
                b.w = 0u;
                uint4* e = (uint4*)(keptbuf + ((size_t)c * KEEP_CAP + rank) * 8);
                e[0] = a; e[1] = b;
            }
        }
    }
}

// ---- Stage 4: global top-100 via hist-select over <=9000 kept entries ----
__global__ __launch_bounds__(1024)
void final_kernel(const u32* __restrict__ keptbuf, const u32* __restrict__ cnt2,
                  float* __restrict__ out) {
    __shared__ u32 hist[NBINS];    // 32 KB
    __shared__ u32 csum[1024];     // 4 KB
    __shared__ u64 ebuf[FCAP];     // 4 KB keys
    __shared__ u32 eidx[FCAP];     // 2 KB payload (keptbuf entry index)
    __shared__ u32 scnt[C_N];
    __shared__ u32 sP;
    __shared__ int sN;
    const int tid = threadIdx.x;
    const int TOT = C_N * KEEP_CAP;   // 9000

    for (int i = tid; i < MAXDET * 7; i += 1024) out[i] = 0.0f;
    for (int i = tid; i < NBINS; i += 1024) hist[i] = 0;
    if (tid < C_N) scnt[tid] = cnt2[tid];
    if (tid == 0) { sN = 0; sP = NBINS - 1; }
    __syncthreads();

    // hist over composite high word (smaller = better -> ascending pivot)
    for (int i = tid; i < TOT; i += 1024) {
        u32 c = (u32)i / KEEP_CAP, pp = (u32)i % KEEP_CAP;
        if (pp < scnt[c]) {
            u32 khi = keptbuf[(size_t)i * 8];   // a.x = ~fkey(s)
            atomicAdd(&hist[khi >> KSH], 1u);
        }
    }
    __syncthreads();
    // ascending chunk sums (8 bins each) + Hillis-Steele scan
    u32 own = 0; const int lo = 8 * tid;
    #pragma unroll
    for (int j = 0; j < 8; ++j) own += hist[lo + j];
    csum[tid] = own;
    __syncthreads();
    for (int off = 1; off < 1024; off <<= 1) {
        u32 v = csum[tid];
        u32 a = (tid >= off) ? csum[tid - off] : 0u;
        __syncthreads();
        csum[tid] = v + a;
        __syncthreads();
    }
    const u32 incl = csum[tid], excl = incl - own;
    if (excl < (u32)MAXDET && incl >= (u32)MAXDET) {
        u32 cum = excl;
        for (int j = 0; j < 8; ++j) {
            u32 h = hist[lo + j];
            if (cum + h >= (u32)MAXDET) { sP = (u32)(lo + j); break; }
            cum += h;
        }
    }
    __syncthreads();
    const u32 P = sP;
    // collect entries with bin <= P
    for (int i = tid; i < TOT; i += 1024) {
        u32 c = (u32)i / KEEP_CAP, pp = (u32)i % KEEP_CAP;
        if (pp < scnt[c]) {
            const uint2 v2 = *((const uint2*)(keptbuf + (size_t)i * 8));
            if ((v2.x >> KSH) <= P) {
                int p = atomicAdd(&sN, 1);
                if (p < FCAP) {
                    ebuf[p] = ((u64)v2.x << 32) | v2.y;
                    eidx[p] = (u32)i;
                }
            }
        }
    }
    __syncthreads();
    const int n = min(sN, FCAP);
    u32 m = 128; while ((int)m < n) m <<= 1;   // 128..512, uniform
    for (int i = tid; i < (int)m; i += 1024) if (i >= n) ebuf[i] = ~0ULL;
    __syncthreads();
    // bitonic sort (key ebuf asc, payload eidx follows)
    for (u32 kk = 2; kk <= m; kk <<= 1) {
        for (u32 j = kk >> 1; j > 0; j >>= 1) {
            u32 i = (u32)tid;
            if (i < m) {
                u32 ixj = i ^ j;
                if (ixj > i) {
                    u64 x = ebuf[i], y = ebuf[ixj];
                    bool up = ((i & kk) == 0);
                    if (up ? (x > y) : (x < y)) {
                        ebuf[i] = y; ebuf[ixj] = x;
                        u32 t = eidx[i]; eidx[i] = eidx[ixj]; eidx[ixj] = t;
                    }
                }
            }
            __syncthreads();
        }
    }
    if (tid < MAXDET && tid < n) {
        u64 comp = ebuf[tid];
        if (comp != ~0ULL) {
            const uint4* e = (const uint4*)(keptbuf + (size_t)eidx[tid] * 8);
            uint4 a = e[0], b = e[1];
            float* o = out + tid * 7;
            o[0] = 0.0f;
            o[1] = __uint_as_float(a.z); o[2] = __uint_as_float(a.w);
            o[3] = __uint_as_float(b.x); o[4] = __uint_as_float(b.y);
            o[5] = __uint_as_float(b.z);
            o[6] = (float)(((u32)comp) >> 9);   // low word = c*512+pos -> class
        }
    }
}

extern "C" void kernel_launch(void* const* d_in, const int* in_sizes, int n_in,
                              void* d_out, int out_size, void* d_ws, size_t ws_size,
                              hipStream_t stream) {
    const float* reg     = (const float*)d_in[1];
    const float* cls     = (const float*)d_in[2];
    const float* anchors = (const float*)d_in[3];
    float* out = (float*)d_out;

    char* ws = (char*)d_ws;
    size_t off = 0;
    auto alloc = [&](size_t bytes) -> void* {
        void* p = ws + off;
        off = (off + bytes + 255) & ~(size_t)255;
        return p;
    };
    u32*    keysT   = (u32*)   alloc((size_t)C_N * A_N * sizeof(u32));          // 39.8 MB
    float4* boxes   = (float4*)alloc((size_t)A_N * sizeof(float4));             // 1.77 MB
    u64*    candbuf = (u64*)   alloc((size_t)C_N * CAND_N * sizeof(u64));       // 1.47 MB
    u32*    keptbuf = (u32*)   alloc((size_t)C_N * KEEP_CAP * 8 * sizeof(u32)); // 288 KB
    u32*    cnt2    = (u32*)   alloc((size_t)C_N * sizeof(u32));
    (void)ws_size;

    prep_kernel<<<T_BLKS, 256, 0, stream>>>(cls, keysT);
    select_kernel<<<S_BLKS + D_BLKS, 256, 0, stream>>>(keysT, anchors, reg, boxes, candbuf);
    snms_kernel<<<C_N, 1024, 0, stream>>>(candbuf, boxes, keptbuf, cnt2);
    final_kernel<<<1, 1024, 0, stream>>>(keptbuf, cnt2, out);
}